// Round 1
// baseline (754.349 us; speedup 1.0000x reference)
//
#include <hip/hip_runtime.h>
#include <cstdint>

#define DEV __device__ __forceinline__

DEV float sigmoidf_(float x){ return 1.f / (1.f + __expf(-x)); }
DEV float siluf_(float x){ return x * sigmoidf_(x); }
DEV float softplusf_(float x){ return x > 20.f ? x : log1pf(__expf(x)); }
DEV float lreluf_(float x){ return x >= 0.f ? x : 0.01f * x; }

// ---------------- K1: conv_pre  x[4][80][2048] (pad3,k7) -> h[4][2048][256]
__global__ __launch_bounds__(256) void k_conv_pre(const float* __restrict__ x,
    const float* __restrict__ w, const float* __restrict__ bias, float* __restrict__ h)
{
    const int b = blockIdx.y;
    const int t0 = blockIdx.x * 16;
    const int c = threadIdx.x;
    __shared__ float sX[80][22];
    for (int idx = threadIdx.x; idx < 80 * 22; idx += 256) {
        int m = idx / 22, tt = idx - m * 22;
        int ta = t0 - 3 + tt;
        sX[m][tt] = (ta >= 0 && ta < 2048) ? x[(b * 80 + m) * 2048 + ta] : 0.f;
    }
    __syncthreads();
    float acc[16];
    float bv = bias[c];
    #pragma unroll
    for (int i = 0; i < 16; i++) acc[i] = bv;
    const float* wrow = w + c * 560;
    for (int m = 0; m < 80; ++m) {
        float xr[22];
        #pragma unroll
        for (int q = 0; q < 22; q++) xr[q] = sX[m][q];
        #pragma unroll
        for (int k = 0; k < 7; k++) {
            float wv = wrow[m * 7 + k];
            #pragma unroll
            for (int tt = 0; tt < 16; tt++) acc[tt] = fmaf(xr[k + tt], wv, acc[tt]);
        }
    }
    for (int tt = 0; tt < 16; tt++)
        h[(b * 2048 + t0 + tt) * 256 + c] = acc[tt];
}

// ---------------- generic fp32 NT GEMM: C[m,n] = act(dot(A[m,:K],B[n,:K]) + bias[n])
// ACT: 0 none, 1 softplus.  PERM: 1 -> x_dbl column interleave (dt | B/C interleaved)
template<int ACT, int PERM>
__global__ __launch_bounds__(256) void k_gemm_nt(const float* __restrict__ A,
    const float* __restrict__ B, const float* __restrict__ bias, float* __restrict__ C,
    int M, int N, int K, int lda, int ldb)
{
    __shared__ float As[16][64];
    __shared__ float Bs[16][64];
    const int bm = blockIdx.y * 64, bn = blockIdx.x * 64;
    const int tid = threadIdx.x;
    const int lm = tid >> 2, lk = (tid & 3) * 4;
    const int tx = tid & 15, ty = tid >> 4;
    float acc[4][4];
    #pragma unroll
    for (int i = 0; i < 4; i++)
        #pragma unroll
        for (int j = 0; j < 4; j++) acc[i][j] = 0.f;
    for (int k0 = 0; k0 < K; k0 += 16) {
        float4 av = make_float4(0.f,0.f,0.f,0.f), bv = make_float4(0.f,0.f,0.f,0.f);
        if (bm + lm < M) av = *(const float4*)(A + (size_t)(bm + lm) * lda + k0 + lk);
        if (bn + lm < N) bv = *(const float4*)(B + (size_t)(bn + lm) * ldb + k0 + lk);
        __syncthreads();
        As[lk + 0][lm] = av.x; As[lk + 1][lm] = av.y; As[lk + 2][lm] = av.z; As[lk + 3][lm] = av.w;
        Bs[lk + 0][lm] = bv.x; Bs[lk + 1][lm] = bv.y; Bs[lk + 2][lm] = bv.z; Bs[lk + 3][lm] = bv.w;
        __syncthreads();
        #pragma unroll
        for (int kk = 0; kk < 16; kk++) {
            float4 a  = *(const float4*)&As[kk][ty * 4];
            float4 b4 = *(const float4*)&Bs[kk][tx * 4];
            acc[0][0] = fmaf(a.x, b4.x, acc[0][0]); acc[0][1] = fmaf(a.x, b4.y, acc[0][1]);
            acc[0][2] = fmaf(a.x, b4.z, acc[0][2]); acc[0][3] = fmaf(a.x, b4.w, acc[0][3]);
            acc[1][0] = fmaf(a.y, b4.x, acc[1][0]); acc[1][1] = fmaf(a.y, b4.y, acc[1][1]);
            acc[1][2] = fmaf(a.y, b4.z, acc[1][2]); acc[1][3] = fmaf(a.y, b4.w, acc[1][3]);
            acc[2][0] = fmaf(a.z, b4.x, acc[2][0]); acc[2][1] = fmaf(a.z, b4.y, acc[2][1]);
            acc[2][2] = fmaf(a.z, b4.z, acc[2][2]); acc[2][3] = fmaf(a.z, b4.w, acc[2][3]);
            acc[3][0] = fmaf(a.w, b4.x, acc[3][0]); acc[3][1] = fmaf(a.w, b4.y, acc[3][1]);
            acc[3][2] = fmaf(a.w, b4.z, acc[3][2]); acc[3][3] = fmaf(a.w, b4.w, acc[3][3]);
        }
    }
    #pragma unroll
    for (int i = 0; i < 4; i++) {
        int m = bm + ty * 4 + i;
        if (m >= M) continue;
        #pragma unroll
        for (int j = 0; j < 4; j++) {
            int n = bn + tx * 4 + j;
            if (n >= N) continue;
            float v = acc[i][j];
            if (bias) v += bias[n];
            if (ACT == 1) v = softplusf_(v);
            int nn = n;
            if (PERM) nn = (n < 16) ? n : (n < 80 ? 16 + 2 * (n - 16) : 17 + 2 * (n - 80));
            C[(size_t)m * N + nn] = v;
        }
    }
}

// ---------------- K3: causal depthwise conv (k=4) + SiLU.  u = xz[:, :512]
__global__ __launch_bounds__(256) void k_dwconv(const float* __restrict__ xz,
    const float* __restrict__ w, const float* __restrict__ bias, float* __restrict__ uc)
{
    int idx = blockIdx.x * 256 + threadIdx.x;     // = i*512 + d
    int i = idx >> 9, d = idx & 511;
    int b = i >> 11, t = i & 2047;
    float4 wv = *(const float4*)(w + d * 4);
    float wk[4] = {wv.x, wv.y, wv.z, wv.w};
    float acc = bias[d];
    const float* base = xz + (size_t)(b * 2048) * 1024 + d;
    #pragma unroll
    for (int k = 0; k < 4; k++) {
        int tt = t - 3 + k;
        if (tt >= 0) acc = fmaf(base[(size_t)tt * 1024], wk[k], acc);
    }
    uc[idx] = siluf_(acc);
}

// ---------------- K5: selective scan. wave per (b,d), lane = n (64 states)
__global__ __launch_bounds__(256) void k_scan(const float* __restrict__ xdbl,
    const float* __restrict__ delta, const float* __restrict__ uc,
    const float* __restrict__ A_log, float* __restrict__ y_scan)
{
    int lane = threadIdx.x & 63;
    int wid = __builtin_amdgcn_readfirstlane((int)(threadIdx.x >> 6));
    int gw = blockIdx.x * 4 + wid;      // = b*512 + d
    int b = gw >> 9, d = gw & 511;
    float A = -__expf(A_log[d * 64 + lane]);
    const float* pBC = xdbl + (size_t)(b * 2048) * 144 + 16 + 2 * lane;
    const float* pD  = delta + (size_t)(b * 2048) * 512 + d;
    const float* pU  = uc    + (size_t)(b * 2048) * 512 + d;
    float h = 0.f, ykeep = 0.f;
    for (int t0 = 0; t0 < 2048; t0 += 8) {
        float p[8];
        #pragma unroll
        for (int j = 0; j < 8; j++) {
            int t = t0 + j;
            float2 bc = *(const float2*)(pBC + (size_t)t * 144);
            float dl = pD[(size_t)t * 512];
            float uu = pU[(size_t)t * 512];
            float r = __expf(dl * A);
            h = fmaf(r, h, dl * uu * bc.x);
            p[j] = h * bc.y;
        }
        #pragma unroll
        for (int off = 32; off >= 1; off >>= 1) {
            #pragma unroll
            for (int j = 0; j < 8; j++) p[j] += __shfl_xor(p[j], off, 64);
        }
        #pragma unroll
        for (int j = 0; j < 8; j++)
            if (lane == ((t0 + j) & 63)) ykeep = p[j];
        if (((t0 + 8) & 63) == 0)
            y_scan[(size_t)gw * 2048 + (t0 & ~63) + lane] = ykeep;
    }
}

// ---------------- K6a: g = (y + uc*Dskip) * silu(z), with LDS transpose of y[b,d,t]
__global__ __launch_bounds__(256) void k_combine(const float* __restrict__ y_scan,
    const float* __restrict__ uc, const float* __restrict__ xz,
    const float* __restrict__ Dskip, float* __restrict__ g)
{
    __shared__ float yt[64][65];
    int b = blockIdx.z, d0 = blockIdx.y * 64, t0 = blockIdx.x * 64;
    int tid = threadIdx.x;
    {
        int dd = tid >> 2, q = tid & 3;
        const float* src = y_scan + (size_t)(b * 512 + d0 + dd) * 2048 + t0 + q * 16;
        #pragma unroll
        for (int v = 0; v < 4; v++) {
            float4 f = *(const float4*)(src + v * 4);
            yt[dd][q * 16 + v * 4 + 0] = f.x;
            yt[dd][q * 16 + v * 4 + 1] = f.y;
            yt[dd][q * 16 + v * 4 + 2] = f.z;
            yt[dd][q * 16 + v * 4 + 3] = f.w;
        }
    }
    __syncthreads();
    int dl = tid & 63, tg = tid >> 6;
    int d = d0 + dl;
    float ds = Dskip[d];
    for (int j = 0; j < 16; j++) {
        int tt = tg * 16 + j;
        int i = b * 2048 + t0 + tt;
        float y = yt[dl][tt];
        float u = uc[(size_t)i * 512 + d];
        float z = xz[(size_t)i * 1024 + 512 + d];
        g[(size_t)i * 512 + d] = (y + u * ds) * siluf_(z);
    }
}

// ---------------- K9: transpose conv_post_w [18][256][7] -> wT [7][18][256]
__global__ void k_transpose_wpost(const float* __restrict__ w, float* __restrict__ wT)
{
    int idx = blockIdx.x * 256 + threadIdx.x;
    if (idx >= 18 * 256 * 7) return;
    int o = idx / 1792, rem = idx - o * 1792;
    int c = rem / 7, k = rem - c * 7;
    wT[k * 4608 + o * 256 + c] = w[idx];
}

// ---------------- K7: lrelu + conv_post (k=7,pad3) + exp/sin epilogue
__global__ __launch_bounds__(256) void k_conv_post(const float* __restrict__ mid,
    const float* __restrict__ wT, const float* __restrict__ bias, float* __restrict__ out)
{
    __shared__ float sX[256][40];
    __shared__ float wk[24 * 256];
    int b = blockIdx.y, t0 = blockIdx.x * 32;
    int tid = threadIdx.x;
    for (int r = 0; r < 38; ++r) {
        int ta = t0 - 3 + r;
        float v = 0.f;
        if (ta >= 0 && ta < 2048) v = lreluf_(mid[(size_t)(b * 2048 + ta) * 256 + tid]);
        sX[tid][r] = v;
    }
    int t = tid & 31, og = tid >> 5;    // 8 groups, o = og + 8j
    float acc[3];
    #pragma unroll
    for (int j = 0; j < 3; j++) { int o = og + 8 * j; acc[j] = (o < 18) ? bias[o] : 0.f; }
    for (int k = 0; k < 7; ++k) {
        __syncthreads();
        for (int idx = tid; idx < 24 * 256; idx += 256)
            wk[idx] = (idx < 18 * 256) ? wT[k * 4608 + idx] : 0.f;
        __syncthreads();
        for (int c = 0; c < 256; ++c) {
            float xv = sX[c][t + k];
            acc[0] = fmaf(xv, wk[og * 256 + c], acc[0]);
            acc[1] = fmaf(xv, wk[(og + 8) * 256 + c], acc[1]);
            acc[2] = fmaf(xv, wk[(og + 16) * 256 + c], acc[2]);
        }
    }
    int ta = t0 + t;
    #pragma unroll
    for (int j = 0; j < 3; j++) {
        int o = og + 8 * j;
        if (o >= 18) continue;
        float v = acc[j];
        if (o < 9) out[(size_t)(b * 9 + o) * 2048 + ta] = __expf(v);
        else       out[73728 + (size_t)(b * 9 + (o - 9)) * 2048 + ta] = __sinf(v);
    }
}

extern "C" void kernel_launch(void* const* d_in, const int* in_sizes, int n_in,
                              void* d_out, int out_size, void* d_ws, size_t ws_size,
                              hipStream_t stream)
{
    const float* x         = (const float*)d_in[0];
    const float* pre_w     = (const float*)d_in[1];
    const float* pre_b     = (const float*)d_in[2];
    const float* inproj_w  = (const float*)d_in[3];
    const float* dw_w      = (const float*)d_in[4];
    const float* dw_b      = (const float*)d_in[5];
    const float* xproj_w   = (const float*)d_in[6];
    const float* dt_w      = (const float*)d_in[7];
    const float* dt_b      = (const float*)d_in[8];
    const float* A_log     = (const float*)d_in[9];
    const float* Dskip     = (const float*)d_in[10];
    const float* outproj_w = (const float*)d_in[11];
    const float* post_w    = (const float*)d_in[12];
    const float* post_b    = (const float*)d_in[13];
    float* out = (float*)d_out;
    float* W = (float*)d_ws;

    float* h_pre   = W;                 // 2,097,152 floats (reused as out_mid)
    float* xz      = W + 2097152;       // 8,388,608
    float* uc      = W + 10485760;      // 4,194,304
    float* x_dbl   = W + 14680064;      // 1,179,648 (cols: dt 0..15, BC interleaved 16..143)
    float* delta   = W + 15859712;      // 4,194,304
    float* y_scan  = W + 20054016;      // 4,194,304
    float* g       = W + 24248320;      // 4,194,304
    float* wTpost  = W + 28442624;      // 32,256
    float* out_mid = h_pre;

    k_conv_pre<<<dim3(128, 4), 256, 0, stream>>>(x, pre_w, pre_b, h_pre);
    k_gemm_nt<0,0><<<dim3(16, 128), 256, 0, stream>>>(h_pre, inproj_w, nullptr, xz,
                                                      8192, 1024, 256, 256, 256);
    k_dwconv<<<16384, 256, 0, stream>>>(xz, dw_w, dw_b, uc);
    k_gemm_nt<0,1><<<dim3(3, 128), 256, 0, stream>>>(uc, xproj_w, nullptr, x_dbl,
                                                     8192, 144, 512, 512, 512);
    k_gemm_nt<1,0><<<dim3(8, 128), 256, 0, stream>>>(x_dbl, dt_w, dt_b, delta,
                                                     8192, 512, 16, 144, 16);
    k_scan<<<512, 256, 0, stream>>>(x_dbl, delta, uc, A_log, y_scan);
    k_combine<<<dim3(32, 8, 4), 256, 0, stream>>>(y_scan, uc, xz, Dskip, g);
    k_gemm_nt<0,0><<<dim3(4, 128), 256, 0, stream>>>(g, outproj_w, nullptr, out_mid,
                                                     8192, 256, 512, 512, 512);
    k_transpose_wpost<<<126, 256, 0, stream>>>(post_w, wTpost);
    k_conv_post<<<dim3(64, 4), 256, 0, stream>>>(out_mid, wTpost, post_b, out);
}